// Round 1
// baseline (348.105 us; speedup 1.0000x reference)
//
#include <hip/hip_runtime.h>
#include <hip/hip_bf16.h>
#include <cstdint>
#include <cstddef>

#define DEVFN static __device__ __forceinline__

// 8 bf16 (4 VGPRs) MFMA A/B fragment; 4 fp32 accumulator
typedef __attribute__((ext_vector_type(8))) short bf16x8;
typedef __attribute__((ext_vector_type(4))) float f32x4;

static constexpr int kB = 8192;
static constexpr int kIN = 1024;
static constexpr int kH = 2048;

DEVFN unsigned short f32_to_bf16(float f) {
  union { float f; unsigned int u; } v; v.f = f;
  unsigned int x = v.u;
  x += 0x7fffu + ((x >> 16) & 1u);   // round-to-nearest-even
  return (unsigned short)(x >> 16);
}
DEVFN float bf16_to_f32(unsigned short u) {
  union { unsigned int u; float f; } v; v.u = (unsigned int)u << 16;
  return v.f;
}

// fp32 -> bf16 cast with strided destination (for building concatenated panels)
__global__ void cast_strided(const float* __restrict__ src, unsigned short* __restrict__ dst,
                             int n, int srcWshift, int dstStride, int dstOff) {
  int i = (blockIdx.x * blockDim.x + threadIdx.x) * 4;
  if (i >= n) return;
  float4 v = *(const float4*)(src + i);
  int row = i >> srcWshift;
  int col = i - (row << srcWshift);
  unsigned short* d = dst + (size_t)row * dstStride + dstOff + col;
  ushort4 o;
  o.x = f32_to_bf16(v.x); o.y = f32_to_bf16(v.y);
  o.z = f32_to_bf16(v.z); o.w = f32_to_bf16(v.w);
  *(ushort4*)d = o;
}

typedef const __attribute__((address_space(1))) unsigned int* gptr_t;
typedef __attribute__((address_space(3))) unsigned int* lptr_t;
DEVFN void gload_lds16(const void* g, void* l) {
  // async global->LDS, 16B per lane (wave-uniform LDS base + lane*16)
  __builtin_amdgcn_global_load_lds((gptr_t)g, (lptr_t)l, 16, 0, 0);
}

// C = A (MxK) * W^T (W is NxK), bias added per-column, epilogue:
//  EPI==0: z = tanh(.)   -> bf16 store to zBuf
//  EPI==1: u = sigmoid(.); out = u*h + (1-u)*z   (h fp32, z bf16 from zBuf)
template<int EPI>
__global__ __launch_bounds__(256, 2)
void gemm_bt(const unsigned short* __restrict__ A,
             const unsigned short* __restrict__ W,
             const float* __restrict__ bias,
             int M, int K, int lda, int ldw,
             unsigned short* __restrict__ zBuf, int ldz,
             const float* __restrict__ hIn,
             float* __restrict__ out, int ldo)
{
  __shared__ unsigned short lA[128 * 32];
  __shared__ unsigned short lB[128 * 32];

  const int nTM = M >> 7;
  const int nwg = gridDim.x;
  int bid = blockIdx.x;
  {  // XCD-aware swizzle (nwg % 8 == 0 in all our launches -> bijective)
    int xcd = bid & 7, loc = bid >> 3;
    bid = xcd * (nwg >> 3) + loc;
  }
  const int bm = bid % nTM, bn = bid / nTM;
  const int rowBase = bm << 7, colBase = bn << 7;

  const int t = threadIdx.x;
  const int l = t & 63;
  const int w = t >> 6;
  const int lr = l & 15, lg = l >> 4;          // lane row / k-group
  const int wr = (w >> 1) << 6, wc = (w & 1) << 6;  // wave's 64x64 quadrant

  // staging: tile is 128x32 bf16 = 8KB; 256 thr * 16B = 4KB per issue -> 2 issues
  const int e0 = t * 8;
  const int e1 = 2048 + t * 8;
  const int r0 = e0 >> 5, c0 = e0 & 31;
  const int r1 = e1 >> 5, c1 = e1 & 31;

  const unsigned short* gA0 = A + (size_t)(rowBase + r0) * lda + c0;
  const unsigned short* gA1 = A + (size_t)(rowBase + r1) * lda + c1;
  const unsigned short* gB0 = W + (size_t)(colBase + r0) * ldw + c0;
  const unsigned short* gB1 = W + (size_t)(colBase + r1) * ldw + c1;

  f32x4 acc[4][4] = {};

  for (int kk = 0; kk < K; kk += 32) {
    gload_lds16(gA0 + kk, &lA[e0]);
    gload_lds16(gA1 + kk, &lA[e1]);
    gload_lds16(gB0 + kk, &lB[e0]);
    gload_lds16(gB1 + kk, &lB[e1]);
    __syncthreads();   // compiler drains vmcnt before s_barrier

    bf16x8 af[4], bfr[4];
#pragma unroll
    for (int m = 0; m < 4; ++m)
      af[m] = *(const bf16x8*)&lA[(wr + m * 16 + lr) * 32 + lg * 8];
#pragma unroll
    for (int n = 0; n < 4; ++n)
      bfr[n] = *(const bf16x8*)&lB[(wc + n * 16 + lr) * 32 + lg * 8];
#pragma unroll
    for (int m = 0; m < 4; ++m)
#pragma unroll
      for (int n = 0; n < 4; ++n)
        acc[m][n] = __builtin_amdgcn_mfma_f32_16x16x32_bf16(af[m], bfr[n], acc[m][n], 0, 0, 0);
    __syncthreads();
  }

  // epilogue; C/D layout: col = lane&15, row = (lane>>4)*4 + reg  [HW-verified]
#pragma unroll
  for (int n = 0; n < 4; ++n) {
    const int c = colBase + wc + n * 16 + lr;
    const float bs = bias[c];
#pragma unroll
    for (int m = 0; m < 4; ++m) {
      const int rb = rowBase + wr + m * 16 + lg * 4;
#pragma unroll
      for (int q = 0; q < 4; ++q) {
        const int r = rb + q;
        const float pre = acc[m][n][q] + bs;
        if (EPI == 0) {
          zBuf[(size_t)r * ldz + c] = f32_to_bf16(tanhf(pre));
        } else {
          const float u = 1.0f / (1.0f + __expf(-pre));
          const float h = hIn[(size_t)r * ldo + c];
          const float z = bf16_to_f32(zBuf[(size_t)r * ldz + c]);
          out[(size_t)r * ldo + c] = u * h + (1.0f - u) * z;
        }
      }
    }
  }
}

extern "C" void kernel_launch(void* const* d_in, const int* in_sizes, int n_in,
                              void* d_out, int out_size, void* d_ws, size_t ws_size,
                              hipStream_t stream) {
  const float* h  = (const float*)d_in[0];   // (B,H)
  const float* x  = (const float*)d_in[1];   // (B,IN)
  const float* Wx = (const float*)d_in[2];   // (H,IN)
  const float* bx = (const float*)d_in[3];   // (H)
  const float* Wh = (const float*)d_in[4];   // (H,H)
  const float* Uz = (const float*)d_in[5];   // (H,H)
  const float* bu = (const float*)d_in[6];   // (H)
  float* out = (float*)d_out;

  unsigned short* ws   = (unsigned short*)d_ws;
  unsigned short* xb   = ws;                          // B*IN     (16 MB)
  unsigned short* Wxb  = xb + (size_t)kB * kIN;       // H*IN     ( 4 MB)
  unsigned short* Wcat = Wxb + (size_t)kH * kIN;      // H*2H     (16 MB)
  unsigned short* Acat = Wcat + (size_t)kH * 2 * kH;  // B*2H     (64 MB)

  const int thr = 256;
  // bf16 casts / panel builds
  cast_strided<<<(kB * kIN / 4) / thr, thr, 0, stream>>>(x,  xb,   kB * kIN, 10, kIN,    0);
  cast_strided<<<(kH * kIN / 4) / thr, thr, 0, stream>>>(Wx, Wxb,  kH * kIN, 10, kIN,    0);
  cast_strided<<<(kH * kH  / 4) / thr, thr, 0, stream>>>(Wh, Wcat, kH * kH,  11, 2 * kH, 0);
  cast_strided<<<(kH * kH  / 4) / thr, thr, 0, stream>>>(Uz, Wcat, kH * kH,  11, 2 * kH, kH);
  cast_strided<<<(kB * kH  / 4) / thr, thr, 0, stream>>>(h,  Acat, kB * kH,  11, 2 * kH, 0);

  const int grid = (kB / 128) * (kH / 128);  // 64 * 16 = 1024

  // GEMM1: z = tanh(x Wx^T + bx) -> bf16 into Acat[:, H:2H]
  gemm_bt<0><<<grid, thr, 0, stream>>>(
      xb, Wxb, bx, kB, kIN, kIN, kIN, Acat + kH, 2 * kH, nullptr, nullptr, 0);

  // GEMM2: u = sigmoid([h|z] [Wh|Uz]^T + bu); out = u*h + (1-u)*z
  gemm_bt<1><<<grid, thr, 0, stream>>>(
      Acat, Wcat, bu, kB, 2 * kH, 2 * kH, 2 * kH, Acat + kH, 2 * kH, h, out, kH);
}

// Round 2
// 220.838 us; speedup vs baseline: 1.5763x; 1.5763x over previous
//
#include <hip/hip_runtime.h>
#include <hip/hip_bf16.h>
#include <cstdint>
#include <cstddef>

#define DEVFN static __device__ __forceinline__

typedef __attribute__((ext_vector_type(8))) short bf16x8;
typedef __attribute__((ext_vector_type(4))) float f32x4;

static constexpr int kB = 8192;
static constexpr int kIN = 1024;
static constexpr int kH = 2048;

DEVFN unsigned short f32_to_bf16(float f) {
  union { float f; unsigned int u; } v; v.f = f;
  unsigned int x = v.u;
  x += 0x7fffu + ((x >> 16) & 1u);   // round-to-nearest-even
  return (unsigned short)(x >> 16);
}
DEVFN float bf16_to_f32(unsigned short u) {
  union { unsigned int u; float f; } v; v.u = (unsigned int)u << 16;
  return v.f;
}

__global__ void cast_strided(const float* __restrict__ src, unsigned short* __restrict__ dst,
                             int n, int srcWshift, int dstStride, int dstOff) {
  int i = (blockIdx.x * blockDim.x + threadIdx.x) * 4;
  if (i >= n) return;
  float4 v = *(const float4*)(src + i);
  int row = i >> srcWshift;
  int col = i - (row << srcWshift);
  unsigned short* d = dst + (size_t)row * dstStride + dstOff + col;
  ushort4 o;
  o.x = f32_to_bf16(v.x); o.y = f32_to_bf16(v.y);
  o.z = f32_to_bf16(v.z); o.w = f32_to_bf16(v.w);
  *(ushort4*)d = o;
}

typedef const __attribute__((address_space(1))) unsigned int* gptr_t;
typedef __attribute__((address_space(3))) unsigned int* lptr_t;
DEVFN void gload16(const unsigned short* g, unsigned short* l) {
  __builtin_amdgcn_global_load_lds((gptr_t)g, (lptr_t)l, 16, 0, 0);
}

DEVFN void barpin() {
  __builtin_amdgcn_s_barrier();
  __builtin_amdgcn_sched_barrier(0);   // no code motion across the barrier
}
#define LGKM0() asm volatile("s_waitcnt lgkmcnt(0)" ::: "memory")
#define VMC4()  asm volatile("s_waitcnt vmcnt(4)" ::: "memory")

// LDS geometry: 8 regions of [128 rows][64 bf16] (16 KiB each) = 128 KiB.
// region = buf*4 + op*2 + half   (op: 0=A, 1=B; half: rows 0-127 / 128-255)
// Swizzle (T2): element col stored at  c ^ ((row&7)*8)  (byte ^= (row&7)<<4).
// global_load_lds writes LINEAR; the global SOURCE col is pre-swizzled (rule 21).

template<int BUF, int QM>
DEVFN void ldA(bf16x8 (&a)[4][2], const unsigned short* lds, int wm, int lr, int lg) {
  const unsigned short* rg = lds + (size_t)(BUF * 4 + wm) * 8192;
#pragma unroll
  for (int mi = 0; mi < 4; ++mi) {
    const int rl = QM * 64 + mi * 16 + lr;
#pragma unroll
    for (int kk = 0; kk < 2; ++kk) {
      const int kel = (kk * 32 + lg * 8) ^ ((rl & 7) * 8);
      a[mi][kk] = *(const bf16x8*)(rg + rl * 64 + kel);
    }
  }
}

template<int BUF, int QN>
DEVFN void ldB(bf16x8 (&b)[4][2], const unsigned short* lds, int wn, int lr, int lg) {
  const unsigned short* rg = lds + (size_t)(BUF * 4 + 2 + (wn >> 1)) * 8192;
#pragma unroll
  for (int ni = 0; ni < 2; ++ni) {
    const int n = QN * 2 + ni;
    const int cl = (wn & 1) * 64 + n * 16 + lr;
#pragma unroll
    for (int kk = 0; kk < 2; ++kk) {
      const int kel = (kk * 32 + lg * 8) ^ ((cl & 7) * 8);
      b[n][kk] = *(const bf16x8*)(rg + cl * 64 + kel);
    }
  }
}

template<int QM, int QN>
DEVFN void mfmaQ(f32x4 (&acc)[8][4], bf16x8 (&a)[4][2], bf16x8 (&b)[4][2]) {
  __builtin_amdgcn_s_setprio(1);
#pragma unroll
  for (int mi = 0; mi < 4; ++mi)
#pragma unroll
    for (int ni = 0; ni < 2; ++ni)
#pragma unroll
      for (int kk = 0; kk < 2; ++kk)
        acc[QM * 4 + mi][QN * 2 + ni] = __builtin_amdgcn_mfma_f32_16x16x32_bf16(
            a[mi][kk], b[QN * 2 + ni][kk], acc[QM * 4 + mi][QN * 2 + ni], 0, 0, 0);
  __builtin_amdgcn_s_setprio(0);
}

// C = A (MxK) * W^T (W NxK), N fixed 2048 tiles-of-256; bias per col.
//  EPI==0: zBuf = bf16(tanh(.));  EPI==1: u=sigmoid(.); out = u*h + (1-u)*z
template<int EPI>
__global__ __launch_bounds__(512, 2)
void gemm256(const unsigned short* __restrict__ A,
             const unsigned short* __restrict__ W,
             const float* __restrict__ bias,
             int M, int K,
             unsigned short* __restrict__ zBuf, int ldz,
             const float* __restrict__ hIn,
             float* __restrict__ out, int ldo)
{
  __shared__ unsigned short lds[8][8192];
  unsigned short* L = &lds[0][0];

  const int nTM = M >> 8;
  const int bm = blockIdx.x % nTM, bn = blockIdx.x / nTM;
  const int rowBase = bm << 8, colBase = bn << 8;

  const int t = threadIdx.x;
  const int l = t & 63;
  const int w = t >> 6;
  const int lr = l & 15, lg = l >> 4;
  const int wm = w >> 2, wn = w & 3;

  // staging addresses: thread t covers lds elems [t*8, t*8+8) of each 8KB slab
  const int srow = t >> 3;                       // 0..63
  const int scol = (t & 7) * 8;                  // 0..56
  const int kcSrc = scol ^ ((srow & 7) * 8);     // inverse-swizzled source col
  const unsigned short* gA = A + (size_t)(rowBase + srow) * K + kcSrc;
  const unsigned short* gB = W + (size_t)(colBase + srow) * K + kcSrc;

  // STAGE(buf, op, half, kt): one 16KB half-tile, 2 x global_load_lds per thread
#define STAGE(BUF, OP, HALF, KT) do {                                          \
    const unsigned short* gs = ((OP) ? gB : gA)                                \
        + (size_t)((HALF) * 128) * K + (size_t)(KT) * 64;                      \
    unsigned short* ld = L + (size_t)((BUF) * 4 + (OP) * 2 + (HALF)) * 8192    \
        + w * 512;                                                             \
    gload16(gs, ld);                                                           \
    gload16(gs + (size_t)64 * K, ld + 4096);                                   \
  } while (0)

  f32x4 acc[8][4] = {};
  bf16x8 a[4][2], b[4][2];

  // prologue: pair0 buf0 (h0..h3) + pair0 buf1 B halves (h6,h7); drain to 4
  STAGE(0, 0, 0, 0); STAGE(0, 0, 1, 0); STAGE(0, 1, 0, 0); STAGE(0, 1, 1, 0);
  STAGE(1, 1, 0, 1); STAGE(1, 1, 1, 1);
  VMC4();
  barpin();

  const int NP = K >> 7;   // pairs of BK=64 K-tiles
  for (int i = 0; i < NP; ++i) {
    const bool more = (i + 1 < NP);
    const int ktb1  = 2 * i + 1;                 // buf1 A halves, pair i
    const int kt0n  = more ? 2 * i + 2 : 2 * i;      // buf0 halves, pair i+1 (clamped: dead region)
    const int kt1n  = more ? 2 * i + 3 : 2 * i + 1;  // buf1 B halves, pair i+1 (clamped)

    // ph1: Q(0,0) of buf0
    ldA<0, 0>(a, L, wm, lr, lg); ldB<0, 0>(b, L, wn, lr, lg);
    STAGE(1, 0, 0, ktb1);
    barpin(); LGKM0();
    mfmaQ<0, 0>(acc, a, b);
    barpin();
    // ph2: Q(0,1)
    ldB<0, 1>(b, L, wn, lr, lg);
    STAGE(1, 0, 1, ktb1);
    barpin(); LGKM0();
    mfmaQ<0, 1>(acc, a, b);
    barpin();
    // ph3: Q(1,0)
    ldA<0, 1>(a, L, wm, lr, lg);
    STAGE(0, 1, 0, kt0n);
    barpin(); LGKM0();
    mfmaQ<1, 0>(acc, a, b);
    barpin();
    // ph4: Q(1,1); drain so buf1 (h4..h7, pair i) is resident before ph5
    STAGE(0, 1, 1, kt0n);
    barpin(); LGKM0();
    mfmaQ<1, 1>(acc, a, b);
    VMC4();
    barpin();
    // ph5: Q(0,0) of buf1
    ldA<1, 0>(a, L, wm, lr, lg); ldB<1, 0>(b, L, wn, lr, lg);
    STAGE(0, 0, 0, kt0n);
    barpin(); LGKM0();
    mfmaQ<0, 0>(acc, a, b);
    barpin();
    // ph6: Q(0,1)
    ldB<1, 1>(b, L, wn, lr, lg);
    STAGE(0, 0, 1, kt0n);
    barpin(); LGKM0();
    mfmaQ<0, 1>(acc, a, b);
    barpin();
    // ph7: Q(1,0)
    ldA<1, 1>(a, L, wm, lr, lg);
    STAGE(1, 1, 0, kt1n);
    barpin(); LGKM0();
    mfmaQ<1, 0>(acc, a, b);
    barpin();
    // ph8: Q(1,1); drain so buf0 (pair i+1) is resident before next ph1
    STAGE(1, 1, 1, kt1n);
    barpin(); LGKM0();
    mfmaQ<1, 1>(acc, a, b);
    VMC4();
    barpin();
  }
#undef STAGE

  // epilogue; C/D layout: col = lane&15, row = (lane>>4)*4 + reg  [HW-verified]
#pragma unroll
  for (int m = 0; m < 8; ++m) {
    const int r0 = rowBase + wm * 128 + m * 16 + lg * 4;
#pragma unroll
    for (int n = 0; n < 4; ++n) {
      const int c = colBase + wn * 64 + n * 16 + lr;
      const float bs = bias[c];
#pragma unroll
      for (int q = 0; q < 4; ++q) {
        const int r = r0 + q;
        const float pre = acc[m][n][q] + bs;
        if (EPI == 0) {
          zBuf[(size_t)r * ldz + c] = f32_to_bf16(tanhf(pre));
        } else {
          const float u = 1.0f / (1.0f + __expf(-pre));
          const float h = hIn[(size_t)r * ldo + c];
          const float z = bf16_to_f32(zBuf[(size_t)r * ldz + c]);
          out[(size_t)r * ldo + c] = u * h + (1.0f - u) * z;
        }
      }
    }
  }
}

extern "C" void kernel_launch(void* const* d_in, const int* in_sizes, int n_in,
                              void* d_out, int out_size, void* d_ws, size_t ws_size,
                              hipStream_t stream) {
  const float* h  = (const float*)d_in[0];   // (B,H)
  const float* x  = (const float*)d_in[1];   // (B,IN)
  const float* Wx = (const float*)d_in[2];   // (H,IN)
  const float* bx = (const float*)d_in[3];   // (H)
  const float* Wh = (const float*)d_in[4];   // (H,H)
  const float* Uz = (const float*)d_in[5];   // (H,H)
  const float* bu = (const float*)d_in[6];   // (H)
  float* out = (float*)d_out;

  unsigned short* ws   = (unsigned short*)d_ws;
  unsigned short* xb   = ws;                          // B*IN
  unsigned short* Wxb  = xb + (size_t)kB * kIN;       // H*IN
  unsigned short* Wcat = Wxb + (size_t)kH * kIN;      // H*2H  ([Wh|Uz])
  unsigned short* Acat = Wcat + (size_t)kH * 2 * kH;  // B*2H  ([h|z])

  const int thr = 256;
  cast_strided<<<(kB * kIN / 4) / thr, thr, 0, stream>>>(x,  xb,   kB * kIN, 10, kIN,    0);
  cast_strided<<<(kH * kIN / 4) / thr, thr, 0, stream>>>(Wx, Wxb,  kH * kIN, 10, kIN,    0);
  cast_strided<<<(kH * kH  / 4) / thr, thr, 0, stream>>>(Wh, Wcat, kH * kH,  11, 2 * kH, 0);
  cast_strided<<<(kH * kH  / 4) / thr, thr, 0, stream>>>(Uz, Wcat, kH * kH,  11, 2 * kH, kH);
  cast_strided<<<(kB * kH  / 4) / thr, thr, 0, stream>>>(h,  Acat, kB * kH,  11, 2 * kH, 0);

  const int grid = (kB / 256) * (kH / 256);  // 32 * 8 = 256 = 1 block/CU

  // GEMM1: z = tanh(x Wx^T + bx) -> bf16 into Acat[:, H:2H]
  gemm256<0><<<grid, 512, 0, stream>>>(
      xb, Wxb, bx, kB, kIN, Acat + kH, 2 * kH, nullptr, nullptr, 0);

  // GEMM2: u = sigmoid([h|z] [Wh|Uz]^T + bu); out = u*h + (1-u)*z
  gemm256<1><<<grid, 512, 0, stream>>>(
      Acat, Wcat, bu, kB, 2 * kH, Acat + kH, 2 * kH, h, out, kH);
}

// Round 3
// 211.393 us; speedup vs baseline: 1.6467x; 1.0447x over previous
//
#include <hip/hip_runtime.h>
#include <hip/hip_bf16.h>
#include <cstdint>
#include <cstddef>

#define DEVFN static __device__ __forceinline__

typedef __attribute__((ext_vector_type(8))) short bf16x8;
typedef __attribute__((ext_vector_type(4))) float f32x4;

static constexpr int kB = 8192;
static constexpr int kIN = 1024;
static constexpr int kH = 2048;

DEVFN unsigned short f32_to_bf16(float f) {
  union { float f; unsigned int u; } v; v.f = f;
  unsigned int x = v.u;
  x += 0x7fffu + ((x >> 16) & 1u);   // round-to-nearest-even
  return (unsigned short)(x >> 16);
}
DEVFN float bf16_to_f32(unsigned short u) {
  union { unsigned int u; float f; } v; v.u = (unsigned int)u << 16;
  return v.f;
}

// one fused cast pass: fp32 -> bf16 for all five panels (vec4 per thread)
__global__ void cast_all(const float* __restrict__ x, const float* __restrict__ Wx,
                         const float* __restrict__ Wh, const float* __restrict__ Uz,
                         const float* __restrict__ h,
                         unsigned short* __restrict__ xb, unsigned short* __restrict__ Wxb,
                         unsigned short* __restrict__ Wcat, unsigned short* __restrict__ Acat) {
  const long i = (long)blockIdx.x * blockDim.x + threadIdx.x;  // vec4 index
  const float* src; unsigned short* dst; int sh, stride, off; long li;
  if (i < 2097152L)      { li = i;            src = x;  dst = xb;   sh = 8; stride = 1024; off = 0; }
  else if (i < 2621440L) { li = i - 2097152L; src = Wx; dst = Wxb;  sh = 8; stride = 1024; off = 0; }
  else if (i < 3670016L) { li = i - 2621440L; src = Wh; dst = Wcat; sh = 9; stride = 4096; off = 0; }
  else if (i < 4718592L) { li = i - 3670016L; src = Uz; dst = Wcat; sh = 9; stride = 4096; off = 2048; }
  else                   { li = i - 4718592L; src = h;  dst = Acat; sh = 9; stride = 4096; off = 0; }
  float4 v = *(const float4*)(src + li * 4);
  const long row = li >> sh;
  const long col = (li & ((1L << sh) - 1)) * 4;
  unsigned short* d = dst + row * stride + off + col;
  ushort4 o;
  o.x = f32_to_bf16(v.x); o.y = f32_to_bf16(v.y);
  o.z = f32_to_bf16(v.z); o.w = f32_to_bf16(v.w);
  *(ushort4*)d = o;
}

typedef const __attribute__((address_space(1))) unsigned int* gptr_t;
typedef __attribute__((address_space(3))) unsigned int* lptr_t;
DEVFN void gload16(const unsigned short* g, unsigned short* l) {
  __builtin_amdgcn_global_load_lds((gptr_t)g, (lptr_t)l, 16, 0, 0);
}

DEVFN void bar() { __builtin_amdgcn_s_barrier(); }
#define LGKM0() asm volatile("s_waitcnt lgkmcnt(0)" ::: "memory")
#define VMC4()  asm volatile("s_waitcnt vmcnt(4)" ::: "memory")

// LDS geometry: 8 regions of [128 rows][64 bf16] (16 KiB each) = 128 KiB.
// region = buf*4 + op*2 + half   (op: 0=A, 1=B; half: rows 0-127 / 128-255)
// Swizzle (T2): element col stored at  c ^ ((row&7)*8)  (byte ^= (row&7)<<4).
// global_load_lds writes LINEAR; the global SOURCE col is pre-swizzled (rule 21).

template<int BUF, int QM>
DEVFN void ldA(bf16x8 (&a)[4][2], const unsigned short* lds, int wm, int lr, int lg) {
  const unsigned short* rg = lds + (size_t)(BUF * 4 + wm) * 8192;
#pragma unroll
  for (int mi = 0; mi < 4; ++mi) {
    const int rl = QM * 64 + mi * 16 + lr;
#pragma unroll
    for (int kk = 0; kk < 2; ++kk) {
      const int kel = (kk * 32 + lg * 8) ^ ((rl & 7) * 8);
      a[mi][kk] = *(const bf16x8*)(rg + rl * 64 + kel);
    }
  }
}

template<int BUF, int QN>
DEVFN void ldB(bf16x8 (&b)[4][2], const unsigned short* lds, int wn, int lr, int lg) {
  const unsigned short* rg = lds + (size_t)(BUF * 4 + 2 + (wn >> 1)) * 8192;
#pragma unroll
  for (int ni = 0; ni < 2; ++ni) {
    const int n = QN * 2 + ni;
    const int cl = (wn & 1) * 64 + n * 16 + lr;
#pragma unroll
    for (int kk = 0; kk < 2; ++kk) {
      const int kel = (kk * 32 + lg * 8) ^ ((cl & 7) * 8);
      b[n][kk] = *(const bf16x8*)(rg + cl * 64 + kel);
    }
  }
}

template<int QM, int QN>
DEVFN void mfmaQ(f32x4 (&acc)[8][4], bf16x8 (&a)[4][2], bf16x8 (&b)[4][2]) {
  __builtin_amdgcn_s_setprio(1);
#pragma unroll
  for (int mi = 0; mi < 4; ++mi)
#pragma unroll
    for (int ni = 0; ni < 2; ++ni)
#pragma unroll
      for (int kk = 0; kk < 2; ++kk)
        acc[QM * 4 + mi][QN * 2 + ni] = __builtin_amdgcn_mfma_f32_16x16x32_bf16(
            a[mi][kk], b[QN * 2 + ni][kk], acc[QM * 4 + mi][QN * 2 + ni], 0, 0, 0);
  __builtin_amdgcn_s_setprio(0);
}

// C = A (MxK) * W^T (W NxK); bias per col.
//  EPI==0: zOut = bf16(tanh(.))           (zOut = Acat z-half, ldhz stride)
//  EPI==1: u = sigmoid(.); out = u*h + (1-u)*z, h/z read bf16 from hzBuf
template<int EPI>
__global__ __launch_bounds__(512, 1)
void gemm256(const unsigned short* __restrict__ A,
             const unsigned short* __restrict__ W,
             const float* __restrict__ bias,
             int M, int K,
             unsigned short* __restrict__ zOut,
             const unsigned short* __restrict__ hzBuf, int ldhz,
             float* __restrict__ out, int ldo)
{
  __shared__ unsigned short lds[8][8192];
  unsigned short* L = &lds[0][0];

  const int nTM = M >> 8;
  const int bm = blockIdx.x % nTM, bn = blockIdx.x / nTM;
  const int rowBase = bm << 8, colBase = bn << 8;

  const int t = threadIdx.x;
  const int l = t & 63;
  const int w = t >> 6;
  const int lr = l & 15, lg = l >> 4;
  const int wm = w >> 2, wn = w & 3;

  // staging addresses: thread t covers lds elems [t*8, t*8+8) of each 8KB slab
  const int srow = t >> 3;                       // 0..63
  const int scol = (t & 7) * 8;                  // 0..56
  const int kcSrc = scol ^ ((srow & 7) * 8);     // inverse-swizzled source col
  const unsigned short* gA = A + (size_t)(rowBase + srow) * K + kcSrc;
  const unsigned short* gB = W + (size_t)(colBase + srow) * K + kcSrc;

  // STAGE(buf, op, half, kt): one 16KB half-tile, 2 x global_load_lds per thread
#define STAGE(BUF, OP, HALF, KT) do {                                          \
    const unsigned short* gs = ((OP) ? gB : gA)                                \
        + (size_t)((HALF) * 128) * K + (size_t)(KT) * 64;                      \
    unsigned short* ld = L + (size_t)((BUF) * 4 + (OP) * 2 + (HALF)) * 8192    \
        + w * 512;                                                             \
    gload16(gs, ld);                                                           \
    gload16(gs + (size_t)64 * K, ld + 4096);                                   \
  } while (0)

  f32x4 acc[8][4] = {};
  bf16x8 a[4][2], b[4][2];

  // prologue: pair0 buf0 (h0..h3) + pair0 buf1 B halves (h6,h7); drain to 4
  STAGE(0, 0, 0, 0); STAGE(0, 0, 1, 0); STAGE(0, 1, 0, 0); STAGE(0, 1, 1, 0);
  STAGE(1, 1, 0, 1); STAGE(1, 1, 1, 1);
  VMC4();
  bar();

  const int NP = K >> 7;   // pairs of BK=64 K-tiles
  for (int i = 0; i < NP; ++i) {
    const bool more = (i + 1 < NP);
    const int ktb1  = 2 * i + 1;                 // buf1 A halves, pair i
    const int kt0n  = more ? 2 * i + 2 : 2 * i;      // buf0 halves, pair i+1 (clamped)
    const int kt1n  = more ? 2 * i + 3 : 2 * i + 1;  // buf1 B halves, pair i+1 (clamped)

    // ph1: Q(0,0) of buf0
    ldA<0, 0>(a, L, wm, lr, lg); ldB<0, 0>(b, L, wn, lr, lg);
    STAGE(1, 0, 0, ktb1);
    bar(); LGKM0();
    mfmaQ<0, 0>(acc, a, b);
    bar();
    // ph2: Q(0,1)
    ldB<0, 1>(b, L, wn, lr, lg);
    STAGE(1, 0, 1, ktb1);
    bar(); LGKM0();
    mfmaQ<0, 1>(acc, a, b);
    bar();
    // ph3: Q(1,0)
    ldA<0, 1>(a, L, wm, lr, lg);
    STAGE(0, 1, 0, kt0n);
    bar(); LGKM0();
    mfmaQ<1, 0>(acc, a, b);
    bar();
    // ph4: Q(1,1); drain so buf1 (pair i) is fully resident before ph5
    STAGE(0, 1, 1, kt0n);
    bar(); LGKM0();
    mfmaQ<1, 1>(acc, a, b);
    VMC4();
    bar();
    // ph5: Q(0,0) of buf1
    ldA<1, 0>(a, L, wm, lr, lg); ldB<1, 0>(b, L, wn, lr, lg);
    STAGE(0, 0, 0, kt0n);
    bar(); LGKM0();
    mfmaQ<0, 0>(acc, a, b);
    bar();
    // ph6: Q(0,1)
    ldB<1, 1>(b, L, wn, lr, lg);
    STAGE(0, 0, 1, kt0n);
    bar(); LGKM0();
    mfmaQ<0, 1>(acc, a, b);
    bar();
    // ph7: Q(1,0)
    ldA<1, 1>(a, L, wm, lr, lg);
    STAGE(1, 1, 0, kt1n);
    bar(); LGKM0();
    mfmaQ<1, 0>(acc, a, b);
    bar();
    // ph8: Q(1,1); drain so buf0 (pair i+1) is resident before next ph1
    STAGE(1, 1, 1, kt1n);
    bar(); LGKM0();
    mfmaQ<1, 1>(acc, a, b);
    VMC4();
    bar();
  }
#undef STAGE

  // epilogue; C/D layout: col = lane&15, row = (lane>>4)*4 + reg  [HW-verified]
#pragma unroll
  for (int m = 0; m < 8; ++m) {
    const int r0 = rowBase + wm * 128 + m * 16 + lg * 4;
#pragma unroll
    for (int n = 0; n < 4; ++n) {
      const int c = colBase + wn * 64 + n * 16 + lr;
      const float bs = bias[c];
#pragma unroll
      for (int q = 0; q < 4; ++q) {
        const int r = r0 + q;
        const float pre = acc[m][n][q] + bs;
        if (EPI == 0) {
          zOut[(size_t)r * ldhz + c] = f32_to_bf16(tanhf(pre));
        } else {
          const float u = 1.0f / (1.0f + __expf(-pre));
          const float hv = bf16_to_f32(hzBuf[(size_t)r * ldhz + c]);
          const float zv = bf16_to_f32(hzBuf[(size_t)r * ldhz + 2048 + c]);
          out[(size_t)r * ldo + c] = u * hv + (1.0f - u) * zv;
        }
      }
    }
  }
}

extern "C" void kernel_launch(void* const* d_in, const int* in_sizes, int n_in,
                              void* d_out, int out_size, void* d_ws, size_t ws_size,
                              hipStream_t stream) {
  const float* h  = (const float*)d_in[0];   // (B,H)
  const float* x  = (const float*)d_in[1];   // (B,IN)
  const float* Wx = (const float*)d_in[2];   // (H,IN)
  const float* bx = (const float*)d_in[3];   // (H)
  const float* Wh = (const float*)d_in[4];   // (H,H)
  const float* Uz = (const float*)d_in[5];   // (H,H)
  const float* bu = (const float*)d_in[6];   // (H)
  float* out = (float*)d_out;

  unsigned short* ws   = (unsigned short*)d_ws;
  unsigned short* xb   = ws;                          // B*IN
  unsigned short* Wxb  = xb + (size_t)kB * kIN;       // H*IN
  unsigned short* Wcat = Wxb + (size_t)kH * kIN;      // H*2H  ([Wh|Uz])
  unsigned short* Acat = Wcat + (size_t)kH * 2 * kH;  // B*2H  ([h|z])

  // all fp32->bf16 casts in one pass: 8,912,896 vec4 units / 256 = 34816 blocks
  cast_all<<<34816, 256, 0, stream>>>(x, Wx, Wh, Uz, h, xb, Wxb, Wcat, Acat);

  const int grid = (kB / 256) * (kH / 256);  // 32 * 8 = 256 = 1 block/CU

  // GEMM1: z = tanh(x Wx^T + bx) -> bf16 into Acat[:, H:2H]
  gemm256<0><<<grid, 512, 0, stream>>>(
      xb, Wxb, bx, kB, kIN, Acat + kH, nullptr, 2 * kH, nullptr, 0);

  // GEMM2: u = sigmoid([h|z] [Wh|Uz]^T + bu); out = u*h + (1-u)*z (h,z bf16)
  gemm256<1><<<grid, 512, 0, stream>>>(
      Acat, Wcat, bu, kB, 2 * kH, nullptr, Acat, 2 * kH, out, kH);
}